// Round 2
// 2650.627 us; speedup vs baseline: 1.2499x; 1.2499x over previous
//
#include <hip/hip_runtime.h>

#define T_STEPS 63
#define NWG 256
#define WG_SIZE 256
#define NA 32
#define NV 224
#define G_U 14   // u/Z reduction groups: 224/16 -> fan-in 16 per address

typedef float floatx4 __attribute__((ext_vector_type(4)));
typedef __bf16 bf16x8 __attribute__((ext_vector_type(8)));

__device__ __forceinline__ unsigned short f2bf(float x) {
  unsigned int u = __builtin_bit_cast(unsigned int, x);
  u += 0x7fffu + ((u >> 16) & 1u);
  return (unsigned short)(u >> 16);
}
__device__ __forceinline__ float sigmoidf(float x) {
  return 1.0f / (1.0f + __expf(-x));
}
__device__ __forceinline__ floatx4 mfma_bf16(bf16x8 a, bf16x8 b, floatx4 c) {
  return __builtin_amdgcn_mfma_f32_16x16x32_bf16(a, b, c, 0, 0, 0);
}
__device__ __forceinline__ floatx4 mfma_fp8(long a, long b, floatx4 c) {
  return __builtin_amdgcn_mfma_f32_16x16x32_fp8_fp8(a, b, c, 0, 0, 0);
}
__device__ __forceinline__ unsigned char f2fp8(float x) {
  return (unsigned char)(__builtin_amdgcn_cvt_pk_fp8_f32(x, x, 0, false) & 0xff);
}

// ---- device-scope (MALL, sc0|sc1) relaxed atomics: no fences, no L2 staleness ----
__device__ __forceinline__ unsigned long long ald64(const void* p) {
  return __hip_atomic_load((const unsigned long long*)p, __ATOMIC_RELAXED, __HIP_MEMORY_SCOPE_AGENT);
}
__device__ __forceinline__ float aldf(const float* p) {
  return __hip_atomic_load(p, __ATOMIC_RELAXED, __HIP_MEMORY_SCOPE_AGENT);
}
__device__ __forceinline__ void astf(float* p, float v) {
  __hip_atomic_store(p, v, __ATOMIC_RELAXED, __HIP_MEMORY_SCOPE_AGENT);
}
__device__ __forceinline__ void astu16(unsigned short* p, unsigned short v) {
  __hip_atomic_store(p, v, __ATOMIC_RELAXED, __HIP_MEMORY_SCOPE_AGENT);
}
__device__ __forceinline__ void astu8(unsigned char* p, unsigned char v) {
  __hip_atomic_store(p, v, __ATOMIC_RELAXED, __HIP_MEMORY_SCOPE_AGENT);
}
__device__ __forceinline__ void afaddf(float* p, float v) {
  __hip_atomic_fetch_add(p, v, __ATOMIC_RELAXED, __HIP_MEMORY_SCOPE_AGENT);
}
__device__ __forceinline__ bf16x8 ld_bf8_at(const void* p) {
  union { unsigned long long q[2]; bf16x8 v; } u;
  u.q[0] = ald64(p);
  u.q[1] = ald64((const char*)p + 8);
  return u.v;
}

// signal: drain this WG's vmem (write-through stores/atomics already at MALL), then +1
__device__ __forceinline__ void signal_flag(int* f) {
  __builtin_amdgcn_s_waitcnt(0);
  __syncthreads();
  if (threadIdx.x == 0)
    __hip_atomic_fetch_add(f, 1, __ATOMIC_RELAXED, __HIP_MEMORY_SCOPE_AGENT);
}
__device__ __forceinline__ void wait_flag(const int* f, int target) {
  if (threadIdx.x == 0) {
    while (__hip_atomic_load(f, __ATOMIC_RELAXED, __HIP_MEMORY_SCOPE_AGENT) < target)
      __builtin_amdgcn_s_sleep(2);
  }
  __syncthreads();
}

// ---- prologue: tiled transpose fp32 -> bf16.  out[c*ostride + ooff + r] = bf16(in[r*C+c])
__global__ void k_transpose(const float* __restrict__ in, unsigned short* __restrict__ out,
                            int R, int C, int ostride, int ooff) {
  __shared__ unsigned short tile[64][65];
  const int r0 = blockIdx.x << 6, c0 = blockIdx.y << 6;
  const int t = threadIdx.x;
  const int tr4 = t >> 6, tc = t & 63;
#pragma unroll
  for (int p = 0; p < 16; ++p) {
    int i = (p << 2) + tr4;
    int r = r0 + i;
    unsigned short v = 0;
    if (r < R) v = f2bf(in[(size_t)r * C + (c0 + tc)]);
    tile[i][tc] = v;
  }
  __syncthreads();
#pragma unroll
  for (int p = 0; p < 16; ++p) {
    int j = (p << 2) + tr4;
    int r = r0 + tc;
    if (r < R) out[(size_t)(c0 + j) * ostride + ooff + r] = tile[tc][j];
  }
}

// ---- prologue: tiled transpose fp32 -> fp8.  out[c*OS + r] = fp8(in[r*C+c])
__global__ void k_transpose_fp8(const float* __restrict__ in, unsigned char* __restrict__ out,
                                int R, int C, long OS) {
  __shared__ unsigned char tile[64][68];
  const int r0 = blockIdx.x << 6, c0 = blockIdx.y << 6;
  const int t = threadIdx.x;
  const int tr4 = t >> 6, tc = t & 63;
#pragma unroll
  for (int p = 0; p < 16; ++p) {
    int i = (p << 2) + tr4;
    int r = r0 + i;
    float v = (r < R) ? in[(size_t)r * C + (c0 + tc)] : 0.f;
    tile[i][tc] = f2fp8(v);
  }
  __syncthreads();
#pragma unroll
  for (int p = 0; p < 16; ++p) {
    int j = (p << 2) + tr4;
    out[(size_t)(c0 + j) * OS + r0 + tc] = tile[tc][j];
  }
}

// ---- prologue: cs_bf[32][160] = bf16(content|style|pad0); out[:,0,:] = E[0]
__global__ void k_init(const float* __restrict__ content, const float* __restrict__ style,
                       const float* __restrict__ E, unsigned short* cs_bf, float* out) {
  const int stride = gridDim.x * blockDim.x;
  const int idx = blockIdx.x * blockDim.x + threadIdx.x;
  for (int i = idx; i < 32 * 160; i += stride) {
    int b = i / 160, k = i - b * 160;
    float v = 0.f;
    if (k < 128)      v = content[b * 128 + k];
    else if (k < 144) v = style[b * 16 + (k - 128)];
    cs_bf[i] = f2bf(v);
  }
  for (int i = idx; i < 32 * 512; i += stride) {
    int b = i >> 9, d = i & 511;
    out[(size_t)b * (64 * 512) + d] = E[d];
  }
}

// LDS layout (byte offsets), per-WG role:
//  vocab WG (wg>=32): Ws8  @0        [144][512] fp8, 8B-group XOR-swizzled by (row&7)
//                     E8T  @73728    [512][160] fp8, 8B-group rotated by (d%20)
//                     e_lds@155648   [32][160]  fp8
//  A WG (wg<32):      wkr  @0        [64][1192] bf16 (rows: gate*16 + d-local)
//                     zbuf @152576   [4][32][16] f32
#define SMEM_BYTES 160768
#define OFF_E8T_L 73728
#define OFF_ELDS_L 155648
#define OFF_ZBUF_L 152576

__global__ void __launch_bounds__(WG_SIZE, 1) k_main(
    const float* __restrict__ bvec,          // [2048]
    const float* __restrict__ bs,            // [32000]
    const unsigned char* __restrict__ Ws8_g, // [32256][512] fp8 (Ws^T)
    const unsigned char* __restrict__ E8T_g, // [512][32768]  fp8 (E^T)
    const unsigned short* __restrict__ WkrT, // [2048][1184]  bf16, k = emb512|cs144|pad16|h512
    const unsigned short* __restrict__ cs_bf,// [32][160] bf16 (content|style|pad0)
    const float* __restrict__ E,             // [32000][512] fp32 (row 0 used at s=0)
    unsigned short* h_bufg,  // [32][512] bf16
    unsigned char* h8,       // [32][512] fp8
    unsigned short* emb_bf,  // [32][512] bf16 normalized soft embedding (single buffer)
    float* u,                // [G_U][32][512] fp32 accumulators (atomic, single buffer)
    float* Zbuf,             // [2][G_U][32] fp32 accumulators (atomic)
    int* hflag, int* pflag, int* eflag,  // [64] stride-16 ints each
    float* out)
{
  const int wg = blockIdx.x;
  const int t  = threadIdx.x;
  const int wv = t >> 6;
  const int lane = t & 63;
  const int q = lane >> 4;
  const int m16 = lane & 15;

  __shared__ __align__(16) char smem[SMEM_BYTES];
  unsigned char* lds_ws  = (unsigned char*)smem;
  unsigned char* lds_e8t = (unsigned char*)(smem + OFF_E8T_L);
  unsigned char* lds_e   = (unsigned char*)(smem + OFF_ELDS_L);
  unsigned short* lds_wkr = (unsigned short*)smem;
  float* zbuf = (float*)(smem + OFF_ZBUF_L);

  if (wg < NA) {
    // ---------------- A-WG: LSTM owner of d-slice [wg*16, wg*16+16) ----------------
    for (int idx = t; idx < 64 * 148; idx += WG_SIZE) {
      int row = idx / 148, grp = idx - row * 148;
      int g = row >> 4, c = row & 15;
      int n = g * 512 + (wg << 4) + c;
      ulong2 v = *(const ulong2*)(WkrT + (size_t)n * 1184 + grp * 8);
      *(ulong2*)((char*)lds_wkr + row * 2384 + grp * 16) = v;
    }
    const int dl = t & 15;
    const float bias0 = bvec[0 * 512 + (wg << 4) + dl];
    const float bias1 = bvec[1 * 512 + (wg << 4) + dl];
    const float bias2 = bvec[2 * 512 + (wg << 4) + dl];
    const float bias3 = bvec[3 * 512 + (wg << 4) + dl];
    float c2[2] = {0.f, 0.f};
    __syncthreads();

    const int mt = wv & 1, g0 = (wv >> 1) << 1;
    const int row = mt * 16 + m16;
    const unsigned short* b0row = lds_wkr + (g0 * 16 + m16) * 1192;
    const unsigned short* b1row = lds_wkr + ((g0 + 1) * 16 + m16) * 1192;
    const int d = (wg << 4) + dl;

    for (int s = 0; s < T_STEPS; ++s) {
      const int pc = s & 1;
      if (s > 0) {
        // all A-WGs' emb writes of step s-1 (and their Z reads) are complete
        wait_flag(eflag + (s - 1) * 16, NA);
        // zero the Z parity consumed last step (next written by vocab at s+1, gated by hflag(s+1))
        if (t < G_U) astf(Zbuf + ((s - 1) & 1) * (G_U * 32) + t * 32 + wg, 0.0f);
      }
      floatx4 accG0 = {0.f, 0.f, 0.f, 0.f}, accG1 = {0.f, 0.f, 0.f, 0.f};
      // --- emb chunks (k 0..511) ---
      if (s == 0) {
#pragma unroll 4
        for (int ks = 0; ks < 16; ++ks) {
          const float* ep = E + ks * 32 + q * 8;
          bf16x8 a;
#pragma unroll
          for (int i = 0; i < 8; ++i) a[i] = (__bf16)ep[i];
          accG0 = mfma_bf16(a, *(const bf16x8*)(b0row + ks * 32 + q * 8), accG0);
          accG1 = mfma_bf16(a, *(const bf16x8*)(b1row + ks * 32 + q * 8), accG1);
        }
      } else {
#pragma unroll 4
        for (int ks = 0; ks < 16; ++ks) {
          bf16x8 a = ld_bf8_at(emb_bf + row * 512 + ks * 32 + q * 8);
          accG0 = mfma_bf16(a, *(const bf16x8*)(b0row + ks * 32 + q * 8), accG0);
          accG1 = mfma_bf16(a, *(const bf16x8*)(b1row + ks * 32 + q * 8), accG1);
        }
      }
      // --- content/style chunks (k 512..671, pad zeros) ---
#pragma unroll
      for (int ks = 16; ks < 21; ++ks) {
        bf16x8 a = *(const bf16x8*)(cs_bf + row * 160 + (ks - 16) * 32 + q * 8);
        accG0 = mfma_bf16(a, *(const bf16x8*)(b0row + ks * 32 + q * 8), accG0);
        accG1 = mfma_bf16(a, *(const bf16x8*)(b1row + ks * 32 + q * 8), accG1);
      }
      // --- h chunks (k 672..1183) ---
      if (s > 0) {
#pragma unroll 4
        for (int ks = 21; ks < 37; ++ks) {
          bf16x8 a = ld_bf8_at(h_bufg + row * 512 + (ks - 21) * 32 + q * 8);
          accG0 = mfma_bf16(a, *(const bf16x8*)(b0row + ks * 32 + q * 8), accG0);
          accG1 = mfma_bf16(a, *(const bf16x8*)(b1row + ks * 32 + q * 8), accG1);
        }
      }
      // --- exchange z via LDS (wave owns (gate-pair, m-tile)) ---
#pragma unroll
      for (int r = 0; r < 4; ++r) {
        zbuf[(g0 * 32 + mt * 16 + q * 4 + r) * 16 + m16] = accG0[r];
        zbuf[((g0 + 1) * 32 + mt * 16 + q * 4 + r) * 16 + m16] = accG1[r];
      }
      __syncthreads();
      // --- LSTM pointwise; stage h (write-through) ---
#pragma unroll
      for (int pp = 0; pp < 2; ++pp) {
        const int b = (pp * 256 + t) >> 4;
        float zi = zbuf[(0 * 32 + b) * 16 + dl] + bias0;
        float zf = zbuf[(1 * 32 + b) * 16 + dl] + bias1;
        float zg = zbuf[(2 * 32 + b) * 16 + dl] + bias2;
        float zo = zbuf[(3 * 32 + b) * 16 + dl] + bias3;
        float iv = sigmoidf(zi), fv = sigmoidf(zf);
        float gv = tanhf(zg),    ov = sigmoidf(zo);
        c2[pp] = fv * c2[pp] + iv * gv;
        float h = ov * tanhf(c2[pp]);
        astu16(h_bufg + b * 512 + d, f2bf(h));
        astu8(h8 + b * 512 + d, f2fp8(h));
      }
      signal_flag(hflag + s * 16);
      wait_flag(pflag + s * 16, NV);
      // --- consume u: reduce G_U group partials for OWN d-slice, normalize, ---
      // --- write out + emb_bf, read-then-zero (single-buffered u is safe:  ---
      // --- vocab's next adds are gated by hflag(s+1), which we signal only ---
      // --- after s_waitcnt(0) drains these zero-stores)                    ---
#pragma unroll
      for (int pp = 0; pp < 2; ++pp) {
        const int b = (pp * 256 + t) >> 4;
        float uv = 0.f, Zv = 0.f;
#pragma unroll
        for (int g = 0; g < G_U; ++g) uv += aldf(u + g * 16384 + b * 512 + d);
#pragma unroll
        for (int g = 0; g < G_U; ++g) Zv += aldf(Zbuf + pc * (G_U * 32) + g * 32 + b);
        float ev = uv / Zv;
        out[(size_t)b * (64 * 512) + (size_t)(s + 1) * 512 + d] = ev;
        astu16(emb_bf + b * 512 + d, f2bf(ev));
#pragma unroll
        for (int g = 0; g < G_U; ++g) astf(u + g * 16384 + b * 512 + d, 0.0f);
      }
      signal_flag(eflag + s * 16);
    }
  } else {
    // ---------------- vocab WG: 144-word slice ----------------
    const int wgv = wg - NA;
    const int gu = wgv >> 4;          // reduction group (16 WGs per group)
    const long j0 = (long)wgv * 144;
    for (int idx = t; idx < 144 * 64; idx += WG_SIZE) {
      int row = idx >> 6, grp = idx & 63;
      long v = *(const long*)(Ws8_g + (j0 + row) * 512 + grp * 8);
      *(long*)(lds_ws + row * 512 + ((grp ^ (row & 7)) << 3)) = v;
    }
    for (int idx = t; idx < 512 * 20; idx += WG_SIZE) {
      int dd = idx / 20, g = idx - dd * 20;
      long v = 0;
      if (g < 18) v = *(const long*)(E8T_g + (size_t)dd * 32768 + j0 + g * 8);
      int grp = g + (dd % 20); if (grp >= 20) grp -= 20;
      *(long*)(lds_e8t + dd * 160 + grp * 8) = v;
    }
    for (int idx = t; idx < (32 * 160) / 8; idx += WG_SIZE) ((long*)lds_e)[idx] = 0;
    __syncthreads();

    for (int s = 0; s < T_STEPS; ++s) {
      wait_flag(hflag + s * 16, NA);
      const int pc = s & 1;
      long ah[2][16];
#pragma unroll
      for (int mt = 0; mt < 2; ++mt)
#pragma unroll
        for (int ks = 0; ks < 16; ++ks)
          ah[mt][ks] = (long)ald64(h8 + (mt * 16 + m16) * 512 + ks * 32 + q * 8);
      // logits: 9 n-tiles round-robin over waves
      for (int tile = wv; tile < 9; tile += 4) {
        const int jl = tile * 16 + m16;
        const unsigned char* wrow = lds_ws + jl * 512;
        const int sw = jl & 7;
        floatx4 acc[2] = {{0,0,0,0},{0,0,0,0}};
#pragma unroll
        for (int ks = 0; ks < 16; ++ks) {
          int g = ks * 4 + q;
          long bfrag = *(const long*)(wrow + ((g ^ sw) << 3));
          acc[0] = mfma_fp8(ah[0][ks], bfrag, acc[0]);
          acc[1] = mfma_fp8(ah[1][ks], bfrag, acc[1]);
        }
        const long jg = j0 + jl;
        const float bsv = bs[jg < 32000 ? jg : 31999];
        const bool valid = (jg < 32000);
#pragma unroll
        for (int mt = 0; mt < 2; ++mt)
#pragma unroll
          for (int r = 0; r < 4; ++r) {
            float e = valid ? __expf(acc[mt][r] + bsv) : 0.0f;
            lds_e[(mt * 16 + q * 4 + r) * 160 + jl] = f2fp8(e);
          }
      }
      __syncthreads();
      // Z partial from the SAME fp8-rounded e (wave 3, lanes 0..31)
      if (t >= 192 && t < 224) {
        const int b = t - 192;
        const unsigned int* rowp = (const unsigned int*)(lds_e + b * 160);
        float z = 0.f;
        for (int g = 0; g < 36; ++g) {
          int w4 = (int)rowp[g];
          z += __builtin_amdgcn_cvt_f32_fp8(w4, 0) + __builtin_amdgcn_cvt_f32_fp8(w4, 1)
             + __builtin_amdgcn_cvt_f32_fp8(w4, 2) + __builtin_amdgcn_cvt_f32_fp8(w4, 3);
        }
        afaddf(Zbuf + pc * (G_U * 32) + gu * 32 + b, z);
      }
      // PV: u[group] += e @ E_slice (atomic fp32 accumulate at MALL)
      // tile order rotated by wgv so concurrent WGs hit disjoint address ranges
      long ae[2][5];
#pragma unroll
      for (int mt = 0; mt < 2; ++mt)
#pragma unroll
        for (int ks = 0; ks < 5; ++ks)
          ae[mt][ks] = *(const long*)(lds_e + (mt * 16 + m16) * 160 + ks * 32 + q * 8);
      for (int i = 0; i < 8; ++i) {
        const int nt = wv + (((i + wgv) & 7) << 2);
        const int dd = nt * 16 + m16;
        const int dm = dd % 20;
        const unsigned char* erow = lds_e8t + dd * 160;
        floatx4 acc2[2] = {{0,0,0,0},{0,0,0,0}};
#pragma unroll
        for (int ks = 0; ks < 5; ++ks) {
          int g = ks * 4 + q + dm; if (g >= 20) g -= 20;
          long bfrag = *(const long*)(erow + (g << 3));
          acc2[0] = mfma_fp8(ae[0][ks], bfrag, acc2[0]);
          acc2[1] = mfma_fp8(ae[1][ks], bfrag, acc2[1]);
        }
#pragma unroll
        for (int mt = 0; mt < 2; ++mt)
#pragma unroll
          for (int r = 0; r < 4; ++r)
            afaddf(u + gu * 16384 + (mt * 16 + q * 4 + r) * 512 + dd, acc2[mt][r]);
      }
      signal_flag(pflag + s * 16);
    }
  }
}

// ---------------- host ----------------
extern "C" void kernel_launch(void* const* d_in, const int* in_sizes, int n_in,
                              void* d_out, int out_size, void* d_ws, size_t ws_size,
                              hipStream_t stream) {
  const float* content = (const float*)d_in[0];
  const float* style   = (const float*)d_in[1];
  const float* E       = (const float*)d_in[2];
  const float* Wk      = (const float*)d_in[3];
  const float* Wr      = (const float*)d_in[4];
  const float* bvec    = (const float*)d_in[5];
  const float* Ws      = (const float*)d_in[6];
  const float* bs      = (const float*)d_in[7];
  float* out = (float*)d_out;
  char* ws = (char*)d_ws;

  constexpr size_t SZ_WS8  = 32256ull * 512;           // 16,515,072
  constexpr size_t SZ_E8T  = 512ull * 32768;           // 16,777,216
  constexpr size_t SZ_WKRT = 2048ull * 1184 * 2;       //  4,849,664
  constexpr size_t SZ_CS   = 32ull * 160 * 2;          //     10,240
  constexpr size_t SZ_HB   = 32ull * 512 * 2;          //     32,768
  constexpr size_t SZ_H8   = 32ull * 512;              //     16,384
  constexpr size_t SZ_U    = (size_t)G_U * 32 * 512 * 4; //  917,504
  constexpr size_t SZ_ZB   = 2ull * G_U * 32 * 4;      //      3,584
  constexpr size_t SZ_FLAG = 3ull * 64 * 16 * 4;       //     12,288
  constexpr size_t SZ_EMB  = 32ull * 512 * 2;          //     32,768
  constexpr size_t OFF_WS8  = 0;
  constexpr size_t OFF_E8T  = OFF_WS8 + SZ_WS8;
  constexpr size_t OFF_WKRT = OFF_E8T + SZ_E8T;
  constexpr size_t OFF_CS   = OFF_WKRT + SZ_WKRT;
  constexpr size_t OFF_HB   = OFF_CS + SZ_CS;
  constexpr size_t OFF_H8   = OFF_HB + SZ_HB;
  constexpr size_t OFF_U    = OFF_H8 + SZ_H8;
  constexpr size_t OFF_ZB   = OFF_U + SZ_U;
  constexpr size_t OFF_FLAG = OFF_ZB + SZ_ZB;
  constexpr size_t OFF_EMB  = OFF_FLAG + SZ_FLAG;

  unsigned char*  Ws8_g = (unsigned char*)(ws + OFF_WS8);
  unsigned char*  E8T_g = (unsigned char*)(ws + OFF_E8T);
  unsigned short* WkrT  = (unsigned short*)(ws + OFF_WKRT);
  unsigned short* cs_bf = (unsigned short*)(ws + OFF_CS);
  unsigned short* h_bufg= (unsigned short*)(ws + OFF_HB);
  unsigned char*  h8    = (unsigned char*)(ws + OFF_H8);
  float* u              = (float*)(ws + OFF_U);
  float* Zbuf           = (float*)(ws + OFF_ZB);
  int* hflag            = (int*)(ws + OFF_FLAG);
  int* pflag            = (int*)(ws + OFF_FLAG + 4096);
  int* eflag            = (int*)(ws + OFF_FLAG + 8192);
  unsigned short* emb_bf= (unsigned short*)(ws + OFF_EMB);

  // zero state (ws poisoned 0xAA each call)
  hipMemsetAsync(Ws8_g, 0, SZ_WS8, stream);   // covers j-pad rows 32000..32256
  hipMemsetAsync(E8T_g, 0, SZ_E8T, stream);   // covers j-pad cols 32000..32768
  hipMemsetAsync(WkrT, 0, SZ_WKRT, stream);   // covers k-pads 656..672, 1184 tail
  hipMemsetAsync(u, 0, SZ_U + SZ_ZB + SZ_FLAG, stream); // u, Zbuf, flags

  // transposed weight copies; Wkr k-layout = Wk(656) | pad16 | Wr(512)
  k_transpose_fp8<<<dim3(8, 500), 256, 0, stream>>>(Ws, Ws8_g, 512, 32000, 512);
  k_transpose_fp8<<<dim3(500, 8), 256, 0, stream>>>(E, E8T_g, 32000, 512, 32768);
  k_transpose<<<dim3(11, 32), 256, 0, stream>>>(Wk, WkrT, 656, 2048, 1184, 0);
  k_transpose<<<dim3(8, 32), 256, 0, stream>>>(Wr, WkrT, 512, 2048, 1184, 672);
  k_init<<<64, 256, 0, stream>>>(content, style, E, cs_bf, out);

  void* args[] = { (void*)&bvec, (void*)&bs, (void*)&Ws8_g, (void*)&E8T_g, (void*)&WkrT,
                   (void*)&cs_bf, (void*)&E, (void*)&h_bufg, (void*)&h8, (void*)&emb_bf,
                   (void*)&u, (void*)&Zbuf, (void*)&hflag, (void*)&pflag, (void*)&eflag,
                   (void*)&out };
  hipLaunchCooperativeKernel((void*)k_main, dim3(NWG), dim3(WG_SIZE), args, 0, stream);

  (void)in_sizes; (void)n_in; (void)out_size; (void)ws_size;
}

// Round 3
// 2308.520 us; speedup vs baseline: 1.4351x; 1.1482x over previous
//
#include <hip/hip_runtime.h>

#define T_STEPS 63
#define NWG 256
#define WG_SIZE 256
#define NA 32
#define NV 224
#define NJC 14   // vocab j-chunks (2304 words each); group = 16 consecutive vocab WGs
#define NDC 16   // d-chunks (32 cols each)

typedef float floatx4 __attribute__((ext_vector_type(4)));
typedef __bf16 bf16x8 __attribute__((ext_vector_type(8)));

__device__ __forceinline__ unsigned short f2bf(float x) {
  unsigned int u = __builtin_bit_cast(unsigned int, x);
  u += 0x7fffu + ((u >> 16) & 1u);
  return (unsigned short)(u >> 16);
}
__device__ __forceinline__ float sigmoidf(float x) {
  return 1.0f / (1.0f + __expf(-x));
}
__device__ __forceinline__ floatx4 mfma_bf16(bf16x8 a, bf16x8 b, floatx4 c) {
  return __builtin_amdgcn_mfma_f32_16x16x32_bf16(a, b, c, 0, 0, 0);
}
__device__ __forceinline__ floatx4 mfma_fp8(long a, long b, floatx4 c) {
  return __builtin_amdgcn_mfma_f32_16x16x32_fp8_fp8(a, b, c, 0, 0, 0);
}
__device__ __forceinline__ unsigned char f2fp8(float x) {
  return (unsigned char)(__builtin_amdgcn_cvt_pk_fp8_f32(x, x, 0, false) & 0xff);
}

// ---- device-scope (MALL) relaxed atomics: no fences, no L2 staleness ----
__device__ __forceinline__ unsigned long long ald64(const void* p) {
  return __hip_atomic_load((const unsigned long long*)p, __ATOMIC_RELAXED, __HIP_MEMORY_SCOPE_AGENT);
}
__device__ __forceinline__ float aldf(const float* p) {
  return __hip_atomic_load(p, __ATOMIC_RELAXED, __HIP_MEMORY_SCOPE_AGENT);
}
__device__ __forceinline__ void astf(float* p, float v) {
  __hip_atomic_store(p, v, __ATOMIC_RELAXED, __HIP_MEMORY_SCOPE_AGENT);
}
__device__ __forceinline__ void astu16(unsigned short* p, unsigned short v) {
  __hip_atomic_store(p, v, __ATOMIC_RELAXED, __HIP_MEMORY_SCOPE_AGENT);
}
__device__ __forceinline__ void astu32(unsigned int* p, unsigned int v) {
  __hip_atomic_store(p, v, __ATOMIC_RELAXED, __HIP_MEMORY_SCOPE_AGENT);
}
__device__ __forceinline__ void astu8(unsigned char* p, unsigned char v) {
  __hip_atomic_store(p, v, __ATOMIC_RELAXED, __HIP_MEMORY_SCOPE_AGENT);
}
__device__ __forceinline__ void afaddf(float* p, float v) {
  __hip_atomic_fetch_add(p, v, __ATOMIC_RELAXED, __HIP_MEMORY_SCOPE_AGENT);
}
__device__ __forceinline__ bf16x8 ld_bf8_at(const void* p) {
  union { unsigned long long q[2]; bf16x8 v; } u;
  u.q[0] = ald64(p);
  u.q[1] = ald64((const char*)p + 8);
  return u.v;
}

// signal: drain this WG's vmem (write-through stores/atomics already at MALL), then +1
__device__ __forceinline__ void signal_flag(int* f) {
  __builtin_amdgcn_s_waitcnt(0);
  __syncthreads();
  if (threadIdx.x == 0)
    __hip_atomic_fetch_add(f, 1, __ATOMIC_RELAXED, __HIP_MEMORY_SCOPE_AGENT);
}
__device__ __forceinline__ void wait_flag(const int* f, int target) {
  if (threadIdx.x == 0) {
    while (__hip_atomic_load(f, __ATOMIC_RELAXED, __HIP_MEMORY_SCOPE_AGENT) < target)
      __builtin_amdgcn_s_sleep(2);
  }
  __syncthreads();
}

// ---- prologue: tiled transpose fp32 -> bf16.  out[c*ostride + ooff + r] = bf16(in[r*C+c])
__global__ void k_transpose(const float* __restrict__ in, unsigned short* __restrict__ out,
                            int R, int C, int ostride, int ooff) {
  __shared__ unsigned short tile[64][65];
  const int r0 = blockIdx.x << 6, c0 = blockIdx.y << 6;
  const int t = threadIdx.x;
  const int tr4 = t >> 6, tc = t & 63;
#pragma unroll
  for (int p = 0; p < 16; ++p) {
    int i = (p << 2) + tr4;
    int r = r0 + i;
    unsigned short v = 0;
    if (r < R) v = f2bf(in[(size_t)r * C + (c0 + tc)]);
    tile[i][tc] = v;
  }
  __syncthreads();
#pragma unroll
  for (int p = 0; p < 16; ++p) {
    int j = (p << 2) + tr4;
    int r = r0 + tc;
    if (r < R) out[(size_t)(c0 + j) * ostride + ooff + r] = tile[tc][j];
  }
}

// ---- prologue: tiled transpose fp32 -> fp8.  out[c*OS + r] = fp8(in[r*C+c])
__global__ void k_transpose_fp8(const float* __restrict__ in, unsigned char* __restrict__ out,
                                int R, int C, long OS) {
  __shared__ unsigned char tile[64][68];
  const int r0 = blockIdx.x << 6, c0 = blockIdx.y << 6;
  const int t = threadIdx.x;
  const int tr4 = t >> 6, tc = t & 63;
#pragma unroll
  for (int p = 0; p < 16; ++p) {
    int i = (p << 2) + tr4;
    int r = r0 + i;
    float v = (r < R) ? in[(size_t)r * C + (c0 + tc)] : 0.f;
    tile[i][tc] = f2fp8(v);
  }
  __syncthreads();
#pragma unroll
  for (int p = 0; p < 16; ++p) {
    int j = (p << 2) + tr4;
    out[(size_t)(c0 + j) * OS + r0 + tc] = tile[tc][j];
  }
}

// ---- prologue: cs_bf[32][160] = bf16(content|style|pad0); out[:,0,:] = E[0]
__global__ void k_init(const float* __restrict__ content, const float* __restrict__ style,
                       const float* __restrict__ E, unsigned short* cs_bf, float* out) {
  const int stride = gridDim.x * blockDim.x;
  const int idx = blockIdx.x * blockDim.x + threadIdx.x;
  for (int i = idx; i < 32 * 160; i += stride) {
    int b = i / 160, k = i - b * 160;
    float v = 0.f;
    if (k < 128)      v = content[b * 128 + k];
    else if (k < 144) v = style[b * 16 + (k - 128)];
    cs_bf[i] = f2bf(v);
  }
  for (int i = idx; i < 32 * 512; i += stride) {
    int b = i >> 9, d = i & 511;
    out[(size_t)b * (64 * 512) + d] = E[d];
  }
}

// LDS layout (byte offsets), per-WG role:
//  vocab WG (wg>=32): Ws8   @0       [144][512] fp8, 8B-group XOR-swizzled by (row&7)
//                     E8TS  @73728   [32][2304] fp8 slice (rows d-local), 8B-group rotated by row
//                     e_lds @147456  [32][160]  fp8
//  A WG (wg<32):      wkr   @0       [64][1192] bf16 (rows: gate*16 + d-local)
//                     zbuf  @152576  [4][32][16] f32
#define SMEM_BYTES 160768
#define OFF_E8TS_L 73728
#define OFF_ELDS_L 147456
#define OFF_ZBUF_L 152576

__global__ void __launch_bounds__(WG_SIZE, 1) k_main(
    const float* __restrict__ bvec,          // [2048]
    const float* __restrict__ bs,            // [32000]
    const unsigned char* __restrict__ Ws8_g, // [32256][512] fp8 (Ws^T)
    const unsigned char* __restrict__ E8T_g, // [512][32768]  fp8 (E^T)
    const unsigned short* __restrict__ WkrT, // [2048][1184]  bf16, k = emb512|cs144|pad16|h512
    const unsigned short* __restrict__ cs_bf,// [32][160] bf16 (content|style|pad0)
    const float* __restrict__ E,             // [32000][512] fp32 (row 0 used at s=0)
    unsigned short* h_bufg,  // [32][512] bf16
    unsigned char* h8,       // [32][512] fp8
    unsigned short* emb_bf,  // [32][512] bf16 normalized soft embedding
    unsigned char* e8g,      // [32][32768] fp8 e (softmax numerator), cols 0..32256 used
    float* Upart,            // [NDC][NJC][32][32] f32 PV partials (plain stores)
    float* Zbuf,             // [2][NJC][32] f32 accumulators (atomic)
    int* hflag, int* eflag, int* qflag, int* pvflag,
    float* out)
{
  const int wg = blockIdx.x;
  const int t  = threadIdx.x;
  const int wv = t >> 6;
  const int lane = t & 63;
  const int q = lane >> 4;
  const int m16 = lane & 15;

  __shared__ __align__(16) char smem[SMEM_BYTES];
  unsigned char* lds_ws   = (unsigned char*)smem;
  unsigned char* lds_e8ts = (unsigned char*)(smem + OFF_E8TS_L);
  unsigned char* lds_e    = (unsigned char*)(smem + OFF_ELDS_L);
  unsigned short* lds_wkr = (unsigned short*)smem;
  float* zbuf = (float*)(smem + OFF_ZBUF_L);

  if (wg < NA) {
    // ---------------- A-WG: LSTM owner of d-slice [wg*16, wg*16+16) ----------------
    for (int idx = t; idx < 64 * 148; idx += WG_SIZE) {
      int row = idx / 148, grp = idx - row * 148;
      int g = row >> 4, c = row & 15;
      int n = g * 512 + (wg << 4) + c;
      ulong2 v = *(const ulong2*)(WkrT + (size_t)n * 1184 + grp * 8);
      *(ulong2*)((char*)lds_wkr + row * 2384 + grp * 16) = v;
    }
    const int dl = t & 15;
    const float bias0 = bvec[0 * 512 + (wg << 4) + dl];
    const float bias1 = bvec[1 * 512 + (wg << 4) + dl];
    const float bias2 = bvec[2 * 512 + (wg << 4) + dl];
    const float bias3 = bvec[3 * 512 + (wg << 4) + dl];
    float c2[2] = {0.f, 0.f};
    __syncthreads();

    const int mt = wv & 1, g0 = (wv >> 1) << 1;
    const int row = mt * 16 + m16;
    const unsigned short* b0row = lds_wkr + (g0 * 16 + m16) * 1192;
    const unsigned short* b1row = lds_wkr + ((g0 + 1) * 16 + m16) * 1192;
    const int d = (wg << 4) + dl;
    const int dc_a = wg >> 1;                 // d-chunk this WG's slice lives in
    const int dl32 = ((wg & 1) << 4) + dl;    // col offset within the 32-wide chunk

    for (int s = 0; s < T_STEPS; ++s) {
      const int pc = s & 1;
      if (s > 0) {
        // all A-WGs' emb writes / Upart+Z reads of step s-1 are complete
        wait_flag(eflag + (s - 1) * 16, NA);
        // zero the Z parity consumed last step (next written by vocab at s+1, gated by hflag(s+1))
        if (t < NJC) astf(Zbuf + ((s - 1) & 1) * (NJC * 32) + t * 32 + wg, 0.0f);
      }
      floatx4 accG0 = {0.f, 0.f, 0.f, 0.f}, accG1 = {0.f, 0.f, 0.f, 0.f};
      // --- emb chunks (k 0..511) ---
      if (s == 0) {
#pragma unroll 4
        for (int ks = 0; ks < 16; ++ks) {
          const float* ep = E + ks * 32 + q * 8;
          bf16x8 a;
#pragma unroll
          for (int i = 0; i < 8; ++i) a[i] = (__bf16)ep[i];
          accG0 = mfma_bf16(a, *(const bf16x8*)(b0row + ks * 32 + q * 8), accG0);
          accG1 = mfma_bf16(a, *(const bf16x8*)(b1row + ks * 32 + q * 8), accG1);
        }
      } else {
#pragma unroll 4
        for (int ks = 0; ks < 16; ++ks) {
          bf16x8 a = ld_bf8_at(emb_bf + row * 512 + ks * 32 + q * 8);
          accG0 = mfma_bf16(a, *(const bf16x8*)(b0row + ks * 32 + q * 8), accG0);
          accG1 = mfma_bf16(a, *(const bf16x8*)(b1row + ks * 32 + q * 8), accG1);
        }
      }
      // --- content/style chunks (k 512..671, pad zeros) ---
#pragma unroll
      for (int ks = 16; ks < 21; ++ks) {
        bf16x8 a = *(const bf16x8*)(cs_bf + row * 160 + (ks - 16) * 32 + q * 8);
        accG0 = mfma_bf16(a, *(const bf16x8*)(b0row + ks * 32 + q * 8), accG0);
        accG1 = mfma_bf16(a, *(const bf16x8*)(b1row + ks * 32 + q * 8), accG1);
      }
      // --- h chunks (k 672..1183) ---
      if (s > 0) {
#pragma unroll 4
        for (int ks = 21; ks < 37; ++ks) {
          bf16x8 a = ld_bf8_at(h_bufg + row * 512 + (ks - 21) * 32 + q * 8);
          accG0 = mfma_bf16(a, *(const bf16x8*)(b0row + ks * 32 + q * 8), accG0);
          accG1 = mfma_bf16(a, *(const bf16x8*)(b1row + ks * 32 + q * 8), accG1);
        }
      }
      // --- exchange z via LDS (wave owns (gate-pair, m-tile)) ---
#pragma unroll
      for (int r = 0; r < 4; ++r) {
        zbuf[(g0 * 32 + mt * 16 + q * 4 + r) * 16 + m16] = accG0[r];
        zbuf[((g0 + 1) * 32 + mt * 16 + q * 4 + r) * 16 + m16] = accG1[r];
      }
      __syncthreads();
      // --- LSTM pointwise; stage h (write-through) ---
#pragma unroll
      for (int pp = 0; pp < 2; ++pp) {
        const int b = (pp * 256 + t) >> 4;
        float zi = zbuf[(0 * 32 + b) * 16 + dl] + bias0;
        float zf = zbuf[(1 * 32 + b) * 16 + dl] + bias1;
        float zg = zbuf[(2 * 32 + b) * 16 + dl] + bias2;
        float zo = zbuf[(3 * 32 + b) * 16 + dl] + bias3;
        float iv = sigmoidf(zi), fv = sigmoidf(zf);
        float gv = tanhf(zg),    ov = sigmoidf(zo);
        c2[pp] = fv * c2[pp] + iv * gv;
        float h = ov * tanhf(c2[pp]);
        astu16(h_bufg + b * 512 + d, f2bf(h));
        astu8(h8 + b * 512 + d, f2fp8(h));
      }
      signal_flag(hflag + s * 16);
      // --- wait for the 14 PV partials covering our d-chunk ---
      wait_flag(pvflag + (s * NDC + dc_a) * 16, NJC);
      // --- reduce 14 jc-partials + Z, normalize, emit out + emb_bf ---
#pragma unroll
      for (int pp = 0; pp < 2; ++pp) {
        const int b = (pp * 256 + t) >> 4;
        float uv = 0.f, Zv = 0.f;
        const float* up = Upart + ((size_t)(dc_a * NJC) * 32 + b) * 32 + dl32;
#pragma unroll
        for (int g = 0; g < NJC; ++g) uv += aldf(up + g * 1024);
#pragma unroll
        for (int g = 0; g < NJC; ++g) Zv += aldf(Zbuf + pc * (NJC * 32) + g * 32 + b);
        float ev = uv / Zv;
        out[(size_t)b * (64 * 512) + (size_t)(s + 1) * 512 + d] = ev;
        astu16(emb_bf + b * 512 + d, f2bf(ev));
      }
      signal_flag(eflag + s * 16);
    }
  } else {
    // ---------------- vocab WG ----------------
    const int wgv = wg - NA;
    const int jc = wgv >> 4;          // j-chunk (2304 words) this WG's group covers
    const int dc = wgv & 15;          // d-chunk (32 cols) this WG reduces in PV
    const long j0 = (long)wgv * 144;  // own 144-word logits slice (inside chunk jc)
    // Ws^T slice -> LDS (for logits)
    for (int idx = t; idx < 144 * 64; idx += WG_SIZE) {
      int row = idx >> 6, grp = idx & 63;
      long v = *(const long*)(Ws8_g + (j0 + row) * 512 + grp * 8);
      *(long*)(lds_ws + row * 512 + ((grp ^ (row & 7)) << 3)) = v;
    }
    // E^T slice [32 d][2304 j] -> LDS, 8B-groups rotated by d-row (bank spread)
    for (int idx = t; idx < 32 * 288; idx += WG_SIZE) {
      int dd = idx / 288, g = idx - dd * 288;
      long v = *(const long*)(E8T_g + (size_t)(dc * 32 + dd) * 32768 + (size_t)jc * 2304 + (size_t)g * 8);
      int g2 = g + dd; if (g2 >= 288) g2 -= 288;
      *(long*)(lds_e8ts + dd * 2304 + (g2 << 3)) = v;
    }
    for (int idx = t; idx < (32 * 160) / 8; idx += WG_SIZE) ((long*)lds_e)[idx] = 0;
    __syncthreads();

    for (int s = 0; s < T_STEPS; ++s) {
      wait_flag(hflag + s * 16, NA);
      const int pc = s & 1;
      long ah[2][16];
#pragma unroll
      for (int mtl = 0; mtl < 2; ++mtl)
#pragma unroll
        for (int ks = 0; ks < 16; ++ks)
          ah[mtl][ks] = (long)ald64(h8 + (mtl * 16 + m16) * 512 + ks * 32 + q * 8);
      // logits: 9 n-tiles round-robin over waves
      for (int tile = wv; tile < 9; tile += 4) {
        const int jl = tile * 16 + m16;
        const unsigned char* wrow = lds_ws + jl * 512;
        const int sw = jl & 7;
        floatx4 acc[2] = {{0,0,0,0},{0,0,0,0}};
#pragma unroll
        for (int ks = 0; ks < 16; ++ks) {
          int g = ks * 4 + q;
          long bfrag = *(const long*)(wrow + ((g ^ sw) << 3));
          acc[0] = mfma_fp8(ah[0][ks], bfrag, acc[0]);
          acc[1] = mfma_fp8(ah[1][ks], bfrag, acc[1]);
        }
        const long jg = j0 + jl;
        const float bsv = bs[jg < 32000 ? jg : 31999];
        const bool valid = (jg < 32000);
#pragma unroll
        for (int mtl = 0; mtl < 2; ++mtl)
#pragma unroll
          for (int r = 0; r < 4; ++r) {
            float e = valid ? __expf(acc[mtl][r] + bsv) : 0.0f;
            lds_e[(mtl * 16 + q * 4 + r) * 160 + jl] = f2fp8(e);
          }
      }
      __syncthreads();
      // publish e slice to global (plain coherent stores, coalesced 4B dwords)
      for (int idx = t; idx < 32 * 36; idx += WG_SIZE) {
        int b = idx / 36, g = idx - b * 36;
        unsigned int v = *(const unsigned int*)(lds_e + b * 160 + g * 4);
        astu32((unsigned int*)(e8g + (size_t)b * 32768 + j0 + g * 4), v);
      }
      // Z partial from the SAME fp8-rounded e (wave 3, lanes 0..31)
      if (t >= 192 && t < 224) {
        const int b = t - 192;
        const unsigned int* rowp = (const unsigned int*)(lds_e + b * 160);
        float z = 0.f;
        for (int g = 0; g < 36; ++g) {
          int w4 = (int)rowp[g];
          z += __builtin_amdgcn_cvt_f32_fp8(w4, 0) + __builtin_amdgcn_cvt_f32_fp8(w4, 1)
             + __builtin_amdgcn_cvt_f32_fp8(w4, 2) + __builtin_amdgcn_cvt_f32_fp8(w4, 3);
        }
        afaddf(Zbuf + pc * (NJC * 32) + jc * 32 + b, z);
      }
      // group-local barrier: all 16 producers of chunk jc have published e
      signal_flag(qflag + (s * NJC + jc) * 16);
      wait_flag(qflag + (s * NJC + jc) * 16, 16);
      // --- PV: full partial e[:, jc-chunk] @ E[jc-chunk, dc*32..+32] ---
      // wave -> output tile: mt = wv&1 (b rows), ntl = wv>>1 (d cols)
      {
        const int mtp = wv & 1, ntl = wv >> 1;
        const int dl_local = ntl * 16 + m16;
        const unsigned char* erow = lds_e8ts + dl_local * 2304;
        const unsigned char* arow = e8g + (size_t)(mtp * 16 + m16) * 32768 + (size_t)jc * 2304;
        floatx4 acc0 = {0,0,0,0}, acc1 = {0,0,0,0};
#pragma unroll 8
        for (int ks = 0; ks < 72; ks += 2) {
          long a0 = (long)ald64(arow + ks * 32 + q * 8);
          long a1 = (long)ald64(arow + (ks + 1) * 32 + q * 8);
          int g0 = ks * 4 + q + dl_local; if (g0 >= 288) g0 -= 288;
          int g1 = g0 + 4;                if (g1 >= 288) g1 -= 288;
          acc0 = mfma_fp8(a0, *(const long*)(erow + (g0 << 3)), acc0);
          acc1 = mfma_fp8(a1, *(const long*)(erow + (g1 << 3)), acc1);
        }
        floatx4 accs = acc0 + acc1;
#pragma unroll
        for (int r = 0; r < 4; ++r)
          astf(Upart + ((size_t)(dc * NJC + jc) * 32 + (mtp * 16 + q * 4 + r)) * 32 + dl_local, accs[r]);
      }
      signal_flag(pvflag + (s * NDC + dc) * 16);
    }
  }
}

// ---------------- host ----------------
extern "C" void kernel_launch(void* const* d_in, const int* in_sizes, int n_in,
                              void* d_out, int out_size, void* d_ws, size_t ws_size,
                              hipStream_t stream) {
  const float* content = (const float*)d_in[0];
  const float* style   = (const float*)d_in[1];
  const float* E       = (const float*)d_in[2];
  const float* Wk      = (const float*)d_in[3];
  const float* Wr      = (const float*)d_in[4];
  const float* bvec    = (const float*)d_in[5];
  const float* Ws      = (const float*)d_in[6];
  const float* bs      = (const float*)d_in[7];
  float* out = (float*)d_out;
  char* ws = (char*)d_ws;

  constexpr size_t SZ_WS8  = 32256ull * 512;             // 16,515,072
  constexpr size_t SZ_E8T  = 512ull * 32768;             // 16,777,216
  constexpr size_t SZ_WKRT = 2048ull * 1184 * 2;         //  4,849,664
  constexpr size_t SZ_CS   = 32ull * 160 * 2;            //     10,240
  constexpr size_t SZ_HB   = 32ull * 512 * 2;            //     32,768
  constexpr size_t SZ_H8   = 32ull * 512;                //     16,384
  constexpr size_t SZ_E8G  = 32ull * 32768;              //  1,048,576
  constexpr size_t SZ_UP   = 16ull * 14 * 32 * 32 * 4;   //    917,504
  constexpr size_t SZ_ZB   = 2ull * 14 * 32 * 4;         //      3,584
  constexpr size_t SZ_HF   = 64ull * 16 * 4;             //      4,096
  constexpr size_t SZ_EF   = 64ull * 16 * 4;             //      4,096
  constexpr size_t SZ_QF   = 63ull * 14 * 16 * 4;        //     56,448
  constexpr size_t SZ_PF   = 63ull * 16 * 16 * 4;        //     64,512
  constexpr size_t SZ_EMB  = 32ull * 512 * 2;            //     32,768
  constexpr size_t OFF_WS8  = 0;
  constexpr size_t OFF_E8T  = OFF_WS8 + SZ_WS8;
  constexpr size_t OFF_WKRT = OFF_E8T + SZ_E8T;
  constexpr size_t OFF_CS   = OFF_WKRT + SZ_WKRT;
  constexpr size_t OFF_HB   = OFF_CS + SZ_CS;
  constexpr size_t OFF_H8   = OFF_HB + SZ_HB;
  constexpr size_t OFF_E8G  = OFF_H8 + SZ_H8;
  constexpr size_t OFF_UP   = OFF_E8G + SZ_E8G;
  constexpr size_t OFF_ZB   = OFF_UP + SZ_UP;
  constexpr size_t OFF_HF   = OFF_ZB + SZ_ZB;
  constexpr size_t OFF_EF   = OFF_HF + SZ_HF;
  constexpr size_t OFF_QF   = OFF_EF + SZ_EF;
  constexpr size_t OFF_PF   = OFF_QF + SZ_QF;
  constexpr size_t OFF_EMB  = OFF_PF + SZ_PF;

  unsigned char*  Ws8_g = (unsigned char*)(ws + OFF_WS8);
  unsigned char*  E8T_g = (unsigned char*)(ws + OFF_E8T);
  unsigned short* WkrT  = (unsigned short*)(ws + OFF_WKRT);
  unsigned short* cs_bf = (unsigned short*)(ws + OFF_CS);
  unsigned short* h_bufg= (unsigned short*)(ws + OFF_HB);
  unsigned char*  h8    = (unsigned char*)(ws + OFF_H8);
  unsigned char*  e8g   = (unsigned char*)(ws + OFF_E8G);
  float* Upart          = (float*)(ws + OFF_UP);
  float* Zbuf           = (float*)(ws + OFF_ZB);
  int* hflag            = (int*)(ws + OFF_HF);
  int* eflag            = (int*)(ws + OFF_EF);
  int* qflag            = (int*)(ws + OFF_QF);
  int* pvflag           = (int*)(ws + OFF_PF);
  unsigned short* emb_bf= (unsigned short*)(ws + OFF_EMB);

  // zero state (ws poisoned 0xAA each call)
  hipMemsetAsync(Ws8_g, 0, SZ_WS8, stream);   // covers j-pad rows 32000..32256
  hipMemsetAsync(E8T_g, 0, SZ_E8T, stream);   // covers j-pad cols 32000..32768
  hipMemsetAsync(WkrT, 0, SZ_WKRT, stream);   // covers k-pads 656..672, 1184 tail
  hipMemsetAsync(ws + OFF_ZB, 0, SZ_ZB + SZ_HF + SZ_EF + SZ_QF + SZ_PF, stream); // Zbuf + all flags

  // transposed weight copies; Wkr k-layout = Wk(656) | pad16 | Wr(512)
  k_transpose_fp8<<<dim3(8, 500), 256, 0, stream>>>(Ws, Ws8_g, 512, 32000, 512);
  k_transpose_fp8<<<dim3(500, 8), 256, 0, stream>>>(E, E8T_g, 32000, 512, 32768);
  k_transpose<<<dim3(11, 32), 256, 0, stream>>>(Wk, WkrT, 656, 2048, 1184, 0);
  k_transpose<<<dim3(8, 32), 256, 0, stream>>>(Wr, WkrT, 512, 2048, 1184, 672);
  k_init<<<64, 256, 0, stream>>>(content, style, E, cs_bf, out);

  void* args[] = { (void*)&bvec, (void*)&bs, (void*)&Ws8_g, (void*)&E8T_g, (void*)&WkrT,
                   (void*)&cs_bf, (void*)&E, (void*)&h_bufg, (void*)&h8, (void*)&emb_bf,
                   (void*)&e8g, (void*)&Upart, (void*)&Zbuf,
                   (void*)&hflag, (void*)&eflag, (void*)&qflag, (void*)&pvflag,
                   (void*)&out };
  hipLaunchCooperativeKernel((void*)k_main, dim3(NWG), dim3(WG_SIZE), args, 0, stream);

  (void)in_sizes; (void)n_in; (void)out_size; (void)ws_size;
}

// Round 4
// 2072.220 us; speedup vs baseline: 1.5988x; 1.1140x over previous
//
#include <hip/hip_runtime.h>

#define T_STEPS 63
#define NWG 256
#define WG_SIZE 256
#define NA 32
#define NV 224
#define NJC 14   // vocab j-chunks (2304 words each); group = 16 consecutive vocab WGs
#define NDC 16   // d-chunks (32 cols each)
#define NHM 15   // hflag mirrors: 14 jc groups + 1 for A-WGs

typedef float floatx4 __attribute__((ext_vector_type(4)));
typedef __bf16 bf16x8 __attribute__((ext_vector_type(8)));

__device__ __forceinline__ unsigned short f2bf(float x) {
  unsigned int u = __builtin_bit_cast(unsigned int, x);
  u += 0x7fffu + ((u >> 16) & 1u);
  return (unsigned short)(u >> 16);
}
__device__ __forceinline__ float sigmoidf(float x) {
  return 1.0f / (1.0f + __expf(-x));
}
__device__ __forceinline__ floatx4 mfma_bf16(bf16x8 a, bf16x8 b, floatx4 c) {
  return __builtin_amdgcn_mfma_f32_16x16x32_bf16(a, b, c, 0, 0, 0);
}
__device__ __forceinline__ floatx4 mfma_fp8(long a, long b, floatx4 c) {
  return __builtin_amdgcn_mfma_f32_16x16x32_fp8_fp8(a, b, c, 0, 0, 0);
}
__device__ __forceinline__ unsigned char f2fp8(float x) {
  return (unsigned char)(__builtin_amdgcn_cvt_pk_fp8_f32(x, x, 0, false) & 0xff);
}

// ---- device-scope (MALL) relaxed atomics: no fences, no L2 staleness ----
__device__ __forceinline__ unsigned long long ald64(const void* p) {
  return __hip_atomic_load((const unsigned long long*)p, __ATOMIC_RELAXED, __HIP_MEMORY_SCOPE_AGENT);
}
__device__ __forceinline__ float aldf(const float* p) {
  return __hip_atomic_load(p, __ATOMIC_RELAXED, __HIP_MEMORY_SCOPE_AGENT);
}
__device__ __forceinline__ void astf(float* p, float v) {
  __hip_atomic_store(p, v, __ATOMIC_RELAXED, __HIP_MEMORY_SCOPE_AGENT);
}
__device__ __forceinline__ void astu16(unsigned short* p, unsigned short v) {
  __hip_atomic_store(p, v, __ATOMIC_RELAXED, __HIP_MEMORY_SCOPE_AGENT);
}
__device__ __forceinline__ void astu32(unsigned int* p, unsigned int v) {
  __hip_atomic_store(p, v, __ATOMIC_RELAXED, __HIP_MEMORY_SCOPE_AGENT);
}
__device__ __forceinline__ void astu8(unsigned char* p, unsigned char v) {
  __hip_atomic_store(p, v, __ATOMIC_RELAXED, __HIP_MEMORY_SCOPE_AGENT);
}
__device__ __forceinline__ void afaddf(float* p, float v) {
  __hip_atomic_fetch_add(p, v, __ATOMIC_RELAXED, __HIP_MEMORY_SCOPE_AGENT);
}
__device__ __forceinline__ void afaddi(int* p, int v) {
  __hip_atomic_fetch_add(p, v, __ATOMIC_RELAXED, __HIP_MEMORY_SCOPE_AGENT);
}
__device__ __forceinline__ bf16x8 ld_bf8_at(const void* p) {
  union { unsigned long long q[2]; bf16x8 v; } u;
  u.q[0] = ald64(p);
  u.q[1] = ald64((const char*)p + 8);
  return u.v;
}

// signal: drain this WG's vmem (write-through stores/atomics already at MALL), then +1
__device__ __forceinline__ void signal_flag(int* f) {
  __builtin_amdgcn_s_waitcnt(0);
  __syncthreads();
  if (threadIdx.x == 0)
    __hip_atomic_fetch_add(f, 1, __ATOMIC_RELAXED, __HIP_MEMORY_SCOPE_AGENT);
}
__device__ __forceinline__ void wait_flag(const int* f, int target) {
  if (threadIdx.x == 0) {
    while (__hip_atomic_load(f, __ATOMIC_RELAXED, __HIP_MEMORY_SCOPE_AGENT) < target)
      __builtin_amdgcn_s_sleep(2);
  }
  __syncthreads();
}

// ---- prologue: tiled transpose fp32 -> bf16.  out[c*ostride + ooff + r] = bf16(in[r*C+c])
__global__ void k_transpose(const float* __restrict__ in, unsigned short* __restrict__ out,
                            int R, int C, int ostride, int ooff) {
  __shared__ unsigned short tile[64][65];
  const int r0 = blockIdx.x << 6, c0 = blockIdx.y << 6;
  const int t = threadIdx.x;
  const int tr4 = t >> 6, tc = t & 63;
#pragma unroll
  for (int p = 0; p < 16; ++p) {
    int i = (p << 2) + tr4;
    int r = r0 + i;
    unsigned short v = 0;
    if (r < R) v = f2bf(in[(size_t)r * C + (c0 + tc)]);
    tile[i][tc] = v;
  }
  __syncthreads();
#pragma unroll
  for (int p = 0; p < 16; ++p) {
    int j = (p << 2) + tr4;
    int r = r0 + tc;
    if (r < R) out[(size_t)(c0 + j) * ostride + ooff + r] = tile[tc][j];
  }
}

// ---- prologue: tiled transpose fp32 -> fp8.  out[c*OS + r] = fp8(in[r*C+c])
__global__ void k_transpose_fp8(const float* __restrict__ in, unsigned char* __restrict__ out,
                                int R, int C, long OS) {
  __shared__ unsigned char tile[64][68];
  const int r0 = blockIdx.x << 6, c0 = blockIdx.y << 6;
  const int t = threadIdx.x;
  const int tr4 = t >> 6, tc = t & 63;
#pragma unroll
  for (int p = 0; p < 16; ++p) {
    int i = (p << 2) + tr4;
    int r = r0 + i;
    float v = (r < R) ? in[(size_t)r * C + (c0 + tc)] : 0.f;
    tile[i][tc] = f2fp8(v);
  }
  __syncthreads();
#pragma unroll
  for (int p = 0; p < 16; ++p) {
    int j = (p << 2) + tr4;
    out[(size_t)(c0 + j) * OS + r0 + tc] = tile[tc][j];
  }
}

// ---- prologue: cs_bf[32][160] = bf16(content|style|pad0); out[:,0,:] = E[0]
__global__ void k_init(const float* __restrict__ content, const float* __restrict__ style,
                       const float* __restrict__ E, unsigned short* cs_bf, float* out) {
  const int stride = gridDim.x * blockDim.x;
  const int idx = blockIdx.x * blockDim.x + threadIdx.x;
  for (int i = idx; i < 32 * 160; i += stride) {
    int b = i / 160, k = i - b * 160;
    float v = 0.f;
    if (k < 128)      v = content[b * 128 + k];
    else if (k < 144) v = style[b * 16 + (k - 128)];
    cs_bf[i] = f2bf(v);
  }
  for (int i = idx; i < 32 * 512; i += stride) {
    int b = i >> 9, d = i & 511;
    out[(size_t)b * (64 * 512) + d] = E[d];
  }
}

// LDS layout (byte offsets), per-WG role:
//  vocab WG (wg>=32): Ws8   @0       [144][512] fp8, 8B-group XOR-swizzled by (row&7)
//                     E8TS  @73728   [32][2304] fp8 slice (rows d-local), 8B-group rotated by row
//                     e_lds @147456  [32][160]  fp8
//  A WG (wg<32):      wkr   @0       [64][1192] bf16 (rows: gate*16 + d-local)
//                     zbuf  @152576  [4][32][16] f32
#define SMEM_BYTES 160768
#define OFF_E8TS_L 73728
#define OFF_ELDS_L 147456
#define OFF_ZBUF_L 152576

__global__ void __launch_bounds__(WG_SIZE, 1) k_main(
    const float* __restrict__ bvec,          // [2048]
    const float* __restrict__ bs,            // [32000]
    const unsigned char* __restrict__ Ws8_g, // [32256][512] fp8 (Ws^T)
    const unsigned char* __restrict__ E8T_g, // [512][32768]  fp8 (E^T)
    const unsigned short* __restrict__ WkrT, // [2048][1184]  bf16, k = emb512|cs144|pad16|h512
    const unsigned short* __restrict__ cs_bf,// [32][160] bf16 (content|style|pad0)
    const float* __restrict__ E,             // [32000][512] fp32 (row 0 used at s=0)
    unsigned short* h_bufg,  // [32][512] bf16
    unsigned char* h8,       // [32][512] fp8
    unsigned short* emb_bf,  // [32][512] bf16 normalized soft embedding
    unsigned char* e8g,      // [32][32768] fp8 e (softmax numerator), cols 0..32256 used
    float* Upart,            // [NDC][NJC][32][32] f32 PV partials (plain stores)
    float* Zbuf,             // [2][NJC][32] f32 accumulators (atomic)
    int* hflag, int* eflag, int* qflag, int* pvflag,
    float* out)
{
  const int wg = blockIdx.x;
  const int t  = threadIdx.x;
  const int wv = t >> 6;
  const int lane = t & 63;
  const int q = lane >> 4;
  const int m16 = lane & 15;

  __shared__ __align__(16) char smem[SMEM_BYTES];
  unsigned char* lds_ws   = (unsigned char*)smem;
  unsigned char* lds_e8ts = (unsigned char*)(smem + OFF_E8TS_L);
  unsigned char* lds_e    = (unsigned char*)(smem + OFF_ELDS_L);
  unsigned short* lds_wkr = (unsigned short*)smem;
  float* zbuf = (float*)(smem + OFF_ZBUF_L);

  if (wg < NA) {
    // ---------------- A-WG: LSTM owner of d-slice [wg*16, wg*16+16) ----------------
    for (int idx = t; idx < 64 * 148; idx += WG_SIZE) {
      int row = idx / 148, grp = idx - row * 148;
      int g = row >> 4, c = row & 15;
      int n = g * 512 + (wg << 4) + c;
      ulong2 v = *(const ulong2*)(WkrT + (size_t)n * 1184 + grp * 8);
      *(ulong2*)((char*)lds_wkr + row * 2384 + grp * 16) = v;
    }
    const int dl = t & 15;
    const float bias0 = bvec[0 * 512 + (wg << 4) + dl];
    const float bias1 = bvec[1 * 512 + (wg << 4) + dl];
    const float bias2 = bvec[2 * 512 + (wg << 4) + dl];
    const float bias3 = bvec[3 * 512 + (wg << 4) + dl];
    float c2[2] = {0.f, 0.f};
    __syncthreads();

    const int mt = wv & 1, g0 = (wv >> 1) << 1;
    const int row = mt * 16 + m16;
    const unsigned short* b0row = lds_wkr + (g0 * 16 + m16) * 1192;
    const unsigned short* b1row = lds_wkr + ((g0 + 1) * 16 + m16) * 1192;
    const int d = (wg << 4) + dl;
    const int dc_a = wg >> 1;                 // d-chunk this WG's slice lives in
    const int dl32 = ((wg & 1) << 4) + dl;    // col offset within the 32-wide chunk

    floatx4 accG0 = {0.f, 0.f, 0.f, 0.f}, accG1 = {0.f, 0.f, 0.f, 0.f};

    for (int s = 0; s < T_STEPS; ++s) {
      const int pc = s & 1;
      if (s == 0) {
        // cs-part
#pragma unroll
        for (int ks = 16; ks < 21; ++ks) {
          bf16x8 a = *(const bf16x8*)(cs_bf + row * 160 + (ks - 16) * 32 + q * 8);
          accG0 = mfma_bf16(a, *(const bf16x8*)(b0row + ks * 32 + q * 8), accG0);
          accG1 = mfma_bf16(a, *(const bf16x8*)(b1row + ks * 32 + q * 8), accG1);
        }
        // emb from E row 0
#pragma unroll 4
        for (int ks = 0; ks < 16; ++ks) {
          const float* ep = E + ks * 32 + q * 8;
          bf16x8 a;
#pragma unroll
          for (int i = 0; i < 8; ++i) a[i] = (__bf16)ep[i];
          accG0 = mfma_bf16(a, *(const bf16x8*)(b0row + ks * 32 + q * 8), accG0);
          accG1 = mfma_bf16(a, *(const bf16x8*)(b1row + ks * 32 + q * 8), accG1);
        }
      } else {
        // emb(s) ready once all A-WGs signaled eflag(s-1); acc already holds h+cs parts
        wait_flag(eflag + (s - 1) * 16, NA);
        // zero the Z parity consumed last step (next written by vocab at s+1, gated by hflag(s+1))
        if (t < NJC) astf(Zbuf + ((s - 1) & 1) * (NJC * 32) + t * 32 + wg, 0.0f);
#pragma unroll 8
        for (int ks = 0; ks < 16; ++ks) {
          bf16x8 a = ld_bf8_at(emb_bf + row * 512 + ks * 32 + q * 8);
          accG0 = mfma_bf16(a, *(const bf16x8*)(b0row + ks * 32 + q * 8), accG0);
          accG1 = mfma_bf16(a, *(const bf16x8*)(b1row + ks * 32 + q * 8), accG1);
        }
      }
      // --- exchange z via LDS (wave owns (gate-pair, m-tile)) ---
#pragma unroll
      for (int r = 0; r < 4; ++r) {
        zbuf[(g0 * 32 + mt * 16 + q * 4 + r) * 16 + m16] = accG0[r];
        zbuf[((g0 + 1) * 32 + mt * 16 + q * 4 + r) * 16 + m16] = accG1[r];
      }
      __syncthreads();
      // --- LSTM pointwise; stage h (write-through) ---
#pragma unroll
      for (int pp = 0; pp < 2; ++pp) {
        const int b = (pp * 256 + t) >> 4;
        float zi = zbuf[(0 * 32 + b) * 16 + dl] + bias0;
        float zf = zbuf[(1 * 32 + b) * 16 + dl] + bias1;
        float zg = zbuf[(2 * 32 + b) * 16 + dl] + bias2;
        float zo = zbuf[(3 * 32 + b) * 16 + dl] + bias3;
        float iv = sigmoidf(zi), fv = sigmoidf(zf);
        float gv = tanhf(zg),    ov = sigmoidf(zo);
        c2[pp] = fv * c2[pp] + iv * gv;
        float h = ov * tanhf(c2[pp]);
        astu16(h_bufg + b * 512 + d, f2bf(h));
        astu8(h8 + b * 512 + d, f2fp8(h));
      }
      // --- signal h ready: drain, then +1 to all NHM mirrors (low poller fan-in each) ---
      __builtin_amdgcn_s_waitcnt(0);
      __syncthreads();
      if (t < NHM) afaddi(hflag + (s * NHM + t) * 16, 1);
      // --- precompute h-part + cs-part of LSTM(s+1) NOW (overlaps vocab logits+PV) ---
      if (s + 1 < T_STEPS) {
        wait_flag(hflag + (s * NHM + (NHM - 1)) * 16, NA);   // all A-WGs' h final
        accG0 = floatx4{0.f, 0.f, 0.f, 0.f};
        accG1 = floatx4{0.f, 0.f, 0.f, 0.f};
#pragma unroll 8
        for (int ks = 21; ks < 37; ++ks) {
          bf16x8 a = ld_bf8_at(h_bufg + row * 512 + (ks - 21) * 32 + q * 8);
          accG0 = mfma_bf16(a, *(const bf16x8*)(b0row + ks * 32 + q * 8), accG0);
          accG1 = mfma_bf16(a, *(const bf16x8*)(b1row + ks * 32 + q * 8), accG1);
        }
#pragma unroll
        for (int ks = 16; ks < 21; ++ks) {
          bf16x8 a = *(const bf16x8*)(cs_bf + row * 160 + (ks - 16) * 32 + q * 8);
          accG0 = mfma_bf16(a, *(const bf16x8*)(b0row + ks * 32 + q * 8), accG0);
          accG1 = mfma_bf16(a, *(const bf16x8*)(b1row + ks * 32 + q * 8), accG1);
        }
      }
      // --- wait for the 14 PV partials covering our d-chunk ---
      wait_flag(pvflag + (s * NDC + dc_a) * 16, NJC);
      // --- reduce 14 jc-partials + Z, normalize, store emb_bf; out deferred ---
      float evs[2];
#pragma unroll
      for (int pp = 0; pp < 2; ++pp) {
        const int b = (pp * 256 + t) >> 4;
        float uv = 0.f, Zv = 0.f;
        const float* up = Upart + ((size_t)(dc_a * NJC) * 32 + b) * 32 + dl32;
#pragma unroll
        for (int g = 0; g < NJC; ++g) uv += aldf(up + g * 1024);
#pragma unroll
        for (int g = 0; g < NJC; ++g) Zv += aldf(Zbuf + pc * (NJC * 32) + g * 32 + b);
        float ev = uv / Zv;
        evs[pp] = ev;
        astu16(emb_bf + b * 512 + d, f2bf(ev));
      }
      signal_flag(eflag + s * 16);
      // --- deferred out stores (pure sink, off the critical chain) ---
#pragma unroll
      for (int pp = 0; pp < 2; ++pp) {
        const int b = (pp * 256 + t) >> 4;
        out[(size_t)b * (64 * 512) + (size_t)(s + 1) * 512 + d] = evs[pp];
      }
    }
  } else {
    // ---------------- vocab WG ----------------
    const int wgv = wg - NA;
    const int jc = wgv >> 4;          // j-chunk (2304 words) this WG's group covers
    const int dc = wgv & 15;          // d-chunk (32 cols) this WG reduces in PV
    const long j0 = (long)wgv * 144;  // own 144-word logits slice (inside chunk jc)
    // Ws^T slice -> LDS (for logits)
    for (int idx = t; idx < 144 * 64; idx += WG_SIZE) {
      int row = idx >> 6, grp = idx & 63;
      long v = *(const long*)(Ws8_g + (j0 + row) * 512 + grp * 8);
      *(long*)(lds_ws + row * 512 + ((grp ^ (row & 7)) << 3)) = v;
    }
    // E^T slice [32 d][2304 j] -> LDS, 8B-groups rotated by d-row (bank spread)
    for (int idx = t; idx < 32 * 288; idx += WG_SIZE) {
      int dd = idx / 288, g = idx - dd * 288;
      long v = *(const long*)(E8T_g + (size_t)(dc * 32 + dd) * 32768 + (size_t)jc * 2304 + (size_t)g * 8);
      int g2 = g + dd; if (g2 >= 288) g2 -= 288;
      *(long*)(lds_e8ts + dd * 2304 + (g2 << 3)) = v;
    }
    for (int idx = t; idx < (32 * 160) / 8; idx += WG_SIZE) ((long*)lds_e)[idx] = 0;
    __syncthreads();

    for (int s = 0; s < T_STEPS; ++s) {
      wait_flag(hflag + (s * NHM + jc) * 16, NA);
      const int pc = s & 1;
      long ah[2][16];
#pragma unroll
      for (int mtl = 0; mtl < 2; ++mtl)
#pragma unroll
        for (int ks = 0; ks < 16; ++ks)
          ah[mtl][ks] = (long)ald64(h8 + (mtl * 16 + m16) * 512 + ks * 32 + q * 8);
      // logits: 9 n-tiles round-robin over waves
      for (int tile = wv; tile < 9; tile += 4) {
        const int jl = tile * 16 + m16;
        const unsigned char* wrow = lds_ws + jl * 512;
        const int sw = jl & 7;
        floatx4 acc[2] = {{0,0,0,0},{0,0,0,0}};
#pragma unroll
        for (int ks = 0; ks < 16; ++ks) {
          int g = ks * 4 + q;
          long bfrag = *(const long*)(wrow + ((g ^ sw) << 3));
          acc[0] = mfma_fp8(ah[0][ks], bfrag, acc[0]);
          acc[1] = mfma_fp8(ah[1][ks], bfrag, acc[1]);
        }
        const long jg = j0 + jl;
        const float bsv = bs[jg < 32000 ? jg : 31999];
        const bool valid = (jg < 32000);
#pragma unroll
        for (int mtl = 0; mtl < 2; ++mtl)
#pragma unroll
          for (int r = 0; r < 4; ++r) {
            float e = valid ? __expf(acc[mtl][r] + bsv) : 0.0f;
            lds_e[(mtl * 16 + q * 4 + r) * 160 + jl] = f2fp8(e);
          }
      }
      __syncthreads();
      // publish e slice to global (plain coherent stores, coalesced 4B dwords)
      for (int idx = t; idx < 32 * 36; idx += WG_SIZE) {
        int b = idx / 36, g = idx - b * 36;
        unsigned int v = *(const unsigned int*)(lds_e + b * 160 + g * 4);
        astu32((unsigned int*)(e8g + (size_t)b * 32768 + j0 + g * 4), v);
      }
      // Z partial from the SAME fp8-rounded e (wave 3, lanes 0..31)
      if (t >= 192 && t < 224) {
        const int b = t - 192;
        const unsigned int* rowp = (const unsigned int*)(lds_e + b * 160);
        float z = 0.f;
        for (int g = 0; g < 36; ++g) {
          int w4 = (int)rowp[g];
          z += __builtin_amdgcn_cvt_f32_fp8(w4, 0) + __builtin_amdgcn_cvt_f32_fp8(w4, 1)
             + __builtin_amdgcn_cvt_f32_fp8(w4, 2) + __builtin_amdgcn_cvt_f32_fp8(w4, 3);
        }
        afaddf(Zbuf + pc * (NJC * 32) + jc * 32 + b, z);
      }
      // group-local barrier: all 16 producers of chunk jc have published e
      signal_flag(qflag + (s * NJC + jc) * 16);
      wait_flag(qflag + (s * NJC + jc) * 16, 16);
      // --- PV: full partial e[:, jc-chunk] @ E[jc-chunk, dc*32..+32] ---
      // wave -> output tile: mt = wv&1 (b rows), ntl = wv>>1 (d cols)
      {
        const int mtp = wv & 1, ntl = wv >> 1;
        const int dl_local = ntl * 16 + m16;
        const unsigned char* erow = lds_e8ts + dl_local * 2304;
        const unsigned char* arow = e8g + (size_t)(mtp * 16 + m16) * 32768 + (size_t)jc * 2304;
        floatx4 acc0 = {0,0,0,0}, acc1 = {0,0,0,0};
#pragma unroll 8
        for (int ks = 0; ks < 72; ks += 2) {
          long a0 = (long)ald64(arow + ks * 32 + q * 8);
          long a1 = (long)ald64(arow + (ks + 1) * 32 + q * 8);
          int g0 = ks * 4 + q + dl_local; if (g0 >= 288) g0 -= 288;
          int g1 = g0 + 4;                if (g1 >= 288) g1 -= 288;
          acc0 = mfma_fp8(a0, *(const long*)(erow + (g0 << 3)), acc0);
          acc1 = mfma_fp8(a1, *(const long*)(erow + (g1 << 3)), acc1);
        }
        floatx4 accs = acc0 + acc1;
#pragma unroll
        for (int r = 0; r < 4; ++r)
          astf(Upart + ((size_t)(dc * NJC + jc) * 32 + (mtp * 16 + q * 4 + r)) * 32 + dl_local, accs[r]);
      }
      signal_flag(pvflag + (s * NDC + dc) * 16);
    }
  }
}

// ---------------- host ----------------
extern "C" void kernel_launch(void* const* d_in, const int* in_sizes, int n_in,
                              void* d_out, int out_size, void* d_ws, size_t ws_size,
                              hipStream_t stream) {
  const float* content = (const float*)d_in[0];
  const float* style   = (const float*)d_in[1];
  const float* E       = (const float*)d_in[2];
  const float* Wk      = (const float*)d_in[3];
  const float* Wr      = (const float*)d_in[4];
  const float* bvec    = (const float*)d_in[5];
  const float* Ws      = (const float*)d_in[6];
  const float* bs      = (const float*)d_in[7];
  float* out = (float*)d_out;
  char* ws = (char*)d_ws;

  constexpr size_t SZ_WS8  = 32256ull * 512;             // 16,515,072
  constexpr size_t SZ_E8T  = 512ull * 32768;             // 16,777,216
  constexpr size_t SZ_WKRT = 2048ull * 1184 * 2;         //  4,849,664
  constexpr size_t SZ_CS   = 32ull * 160 * 2;            //     10,240
  constexpr size_t SZ_HB   = 32ull * 512 * 2;            //     32,768
  constexpr size_t SZ_H8   = 32ull * 512;                //     16,384
  constexpr size_t SZ_E8G  = 32ull * 32768;              //  1,048,576
  constexpr size_t SZ_UP   = 16ull * 14 * 32 * 32 * 4;   //    917,504
  constexpr size_t SZ_ZB   = 2ull * 14 * 32 * 4;         //      3,584
  constexpr size_t SZ_HF   = 64ull * 15 * 16 * 4;        //     61,440
  constexpr size_t SZ_EF   = 64ull * 16 * 4;             //      4,096
  constexpr size_t SZ_QF   = 63ull * 14 * 16 * 4;        //     56,448
  constexpr size_t SZ_PF   = 63ull * 16 * 16 * 4;        //     64,512
  constexpr size_t SZ_EMB  = 32ull * 512 * 2;            //     32,768
  constexpr size_t OFF_WS8  = 0;
  constexpr size_t OFF_E8T  = OFF_WS8 + SZ_WS8;
  constexpr size_t OFF_WKRT = OFF_E8T + SZ_E8T;
  constexpr size_t OFF_CS   = OFF_WKRT + SZ_WKRT;
  constexpr size_t OFF_HB   = OFF_CS + SZ_CS;
  constexpr size_t OFF_H8   = OFF_HB + SZ_HB;
  constexpr size_t OFF_E8G  = OFF_H8 + SZ_H8;
  constexpr size_t OFF_UP   = OFF_E8G + SZ_E8G;
  constexpr size_t OFF_ZB   = OFF_UP + SZ_UP;
  constexpr size_t OFF_HF   = OFF_ZB + SZ_ZB;
  constexpr size_t OFF_EF   = OFF_HF + SZ_HF;
  constexpr size_t OFF_QF   = OFF_EF + SZ_EF;
  constexpr size_t OFF_PF   = OFF_QF + SZ_QF;
  constexpr size_t OFF_EMB  = OFF_PF + SZ_PF;

  unsigned char*  Ws8_g = (unsigned char*)(ws + OFF_WS8);
  unsigned char*  E8T_g = (unsigned char*)(ws + OFF_E8T);
  unsigned short* WkrT  = (unsigned short*)(ws + OFF_WKRT);
  unsigned short* cs_bf = (unsigned short*)(ws + OFF_CS);
  unsigned short* h_bufg= (unsigned short*)(ws + OFF_HB);
  unsigned char*  h8    = (unsigned char*)(ws + OFF_H8);
  unsigned char*  e8g   = (unsigned char*)(ws + OFF_E8G);
  float* Upart          = (float*)(ws + OFF_UP);
  float* Zbuf           = (float*)(ws + OFF_ZB);
  int* hflag            = (int*)(ws + OFF_HF);
  int* eflag            = (int*)(ws + OFF_EF);
  int* qflag            = (int*)(ws + OFF_QF);
  int* pvflag           = (int*)(ws + OFF_PF);
  unsigned short* emb_bf= (unsigned short*)(ws + OFF_EMB);

  // zero state (ws poisoned 0xAA each call)
  hipMemsetAsync(Ws8_g, 0, SZ_WS8, stream);   // covers j-pad rows 32000..32256
  hipMemsetAsync(E8T_g, 0, SZ_E8T, stream);   // covers j-pad cols 32000..32768
  hipMemsetAsync(WkrT, 0, SZ_WKRT, stream);   // covers k-pads 656..672, 1184 tail
  hipMemsetAsync(ws + OFF_ZB, 0, SZ_ZB + SZ_HF + SZ_EF + SZ_QF + SZ_PF, stream); // Zbuf + all flags

  // transposed weight copies; Wkr k-layout = Wk(656) | pad16 | Wr(512)
  k_transpose_fp8<<<dim3(8, 500), 256, 0, stream>>>(Ws, Ws8_g, 512, 32000, 512);
  k_transpose_fp8<<<dim3(500, 8), 256, 0, stream>>>(E, E8T_g, 32000, 512, 32768);
  k_transpose<<<dim3(11, 32), 256, 0, stream>>>(Wk, WkrT, 656, 2048, 1184, 0);
  k_transpose<<<dim3(8, 32), 256, 0, stream>>>(Wr, WkrT, 512, 2048, 1184, 672);
  k_init<<<64, 256, 0, stream>>>(content, style, E, cs_bf, out);

  void* args[] = { (void*)&bvec, (void*)&bs, (void*)&Ws8_g, (void*)&E8T_g, (void*)&WkrT,
                   (void*)&cs_bf, (void*)&E, (void*)&h_bufg, (void*)&h8, (void*)&emb_bf,
                   (void*)&e8g, (void*)&Upart, (void*)&Zbuf,
                   (void*)&hflag, (void*)&eflag, (void*)&qflag, (void*)&pvflag,
                   (void*)&out };
  hipLaunchCooperativeKernel((void*)k_main, dim3(NWG), dim3(WG_SIZE), args, 0, stream);

  (void)in_sizes; (void)n_in; (void)out_size; (void)ws_size;
}